// Round 11
// baseline (1052.444 us; speedup 1.0000x reference)
//
#include <hip/hip_runtime.h>
#include <math.h>

#define BATCH 4
#define SEQ   2048
#define DM    512
#define DI    1024
#define DS    16
#define DR    32
#define BL    (BATCH*SEQ)   // 8192 tokens

#define CH 128              // scan chunk length
#define NC (SEQ/CH)         // 16 chunks per sequence
#define TG 32               // delta t-group (MFMA sub-chunk)

typedef __attribute__((ext_vector_type(8))) short short8_t;   // 8 bf16 = 4 VGPRs
typedef __attribute__((ext_vector_type(4))) float f32x4_t;    // MFMA acc
typedef unsigned short ushort_t;

// fast sigmoid: v_exp_f32 + v_rcp_f32
__device__ __forceinline__ float sigmoidf_(float x){
    return __builtin_amdgcn_rcpf(1.f + __expf(-x));
}

// fp32 -> bf16 bits (RNE)
__device__ __forceinline__ ushort_t f2bf(float f){
    unsigned int u = __float_as_uint(f);
    unsigned int r = (u + 0x7fffu + ((u >> 16) & 1u)) >> 16;
    return (ushort_t)r;
}
__device__ __forceinline__ float bf2f(ushort_t b){
    return __uint_as_float(((unsigned int)b) << 16);
}

// async global->LDS, 16 B per lane
__device__ __forceinline__ void gload16(const ushort_t* g, ushort_t* lds){
    __builtin_amdgcn_global_load_lds(
        (const __attribute__((address_space(1))) unsigned int*)g,
        (__attribute__((address_space(3))) unsigned int*)lds, 16, 0, 0);
}

// ---------------- FFT filter as circulant kernel ----------------
__global__ void build_filter_kernel(const float* __restrict__ fre,
                                    const float* __restrict__ fim,
                                    const float* __restrict__ cut,
                                    float* __restrict__ rker)
{
    int j = blockIdx.x;
    int t = threadIdx.x;
    float c0 = cut[0];
    double acc = 0.0;
    for (int k = t; k < 512; k += 256) {
        float fr = (float)(k < 256 ? k : k - 512) / 512.0f;
        float mask = (fr >= c0 || fr <= -c0) ? 1.f : 0.f;
        double gre = (double)mask + (double)fre[k];
        double gim = (double)fim[k];
        int pr = (j * k) & 511;
        double ang = 6.283185307179586476925286766559 * (double)pr / 512.0;
        acc += gre * cos(ang) - gim * sin(ang);
    }
    #pragma unroll
    for (int o = 32; o > 0; o >>= 1) acc += __shfl_xor(acc, o);
    __shared__ double sd[4];
    int w = t >> 6;
    if ((t & 63) == 0) sd[w] = acc;
    __syncthreads();
    if (t == 0) rker[j] = (float)((sd[0] + sd[1] + sd[2] + sd[3]) / 512.0);
}

__global__ void circ_expand_kernel(const float* __restrict__ rker, ushort_t* __restrict__ Mc)
{
    int n = blockIdx.x, m = threadIdx.x;
    Mc[n*512 + m] = f2bf(rker[(n - m) & 511]);
}

__global__ void cast4_kernel(const float* __restrict__ in, ushort_t* __restrict__ out, int n4)
{
    int i = blockIdx.x*256 + threadIdx.x;
    if (i < n4) {
        float4 v = ((const float4*)in)[i];
        unsigned int lo = (unsigned int)f2bf(v.x) | ((unsigned int)f2bf(v.y) << 16);
        unsigned int hi = (unsigned int)f2bf(v.z) | ((unsigned int)f2bf(v.w) << 16);
        ((uint2*)out)[i] = make_uint2(lo, hi);
    }
}

// xproj weight: 64x1024 fp32 -> 128x1024 bf16 zero-padded
__global__ void cast_xproj_kernel(const float* __restrict__ in, ushort_t* __restrict__ out)
{
    int i = blockIdx.x*256 + threadIdx.x;
    int r = i >> 10;
    out[i] = (r < 64) ? f2bf(in[i]) : (ushort_t)0;
}

// reduce 4 split-K partials over 3BL x 64 -> compact fp32 B/C (cols 32..63)
// and bf16 dt-input (cols 0..31)
__global__ void reduce_xd_kernel(const float* __restrict__ xdp,
                                 float* __restrict__ xdbc,
                                 ushort_t* __restrict__ dti)
{
    int i = blockIdx.x*256 + threadIdx.x;   // 3BL*64
    const size_t S = (size_t)3*BL*64;
    float s = xdp[i] + xdp[i+S] + xdp[i+2*S] + xdp[i+3*S];
    int col = i & 63;
    int row = i >> 6;
    if (col < 32) dti[(size_t)row*32 + col] = f2bf(s);
    else          xdbc[(size_t)row*32 + col - 32] = s;
}

// sum 3 branch yg (bf16) -> bf16, vectorized 8/thread
__global__ void sum3_kernel(const ushort_t* __restrict__ a, ushort_t* __restrict__ out)
{
    int i = blockIdx.x*256 + threadIdx.x;   // BL*DI/8
    const size_t S = (size_t)BL*DI/8;
    uint4 v0 = ((const uint4*)a)[i];
    uint4 v1 = ((const uint4*)a)[i+S];
    uint4 v2 = ((const uint4*)a)[i+2*S];
    unsigned int u0[4]={v0.x,v0.y,v0.z,v0.w}, u1[4]={v1.x,v1.y,v1.z,v1.w}, u2[4]={v2.x,v2.y,v2.z,v2.w};
    unsigned int ov[4];
    #pragma unroll
    for (int q=0;q<4;++q) {
        float lo = bf2f((ushort_t)(u0[q]&0xffff)) + bf2f((ushort_t)(u1[q]&0xffff)) + bf2f((ushort_t)(u2[q]&0xffff));
        float hi = bf2f((ushort_t)(u0[q]>>16))    + bf2f((ushort_t)(u1[q]>>16))    + bf2f((ushort_t)(u2[q]>>16));
        ov[q] = (unsigned int)f2bf(lo) | ((unsigned int)f2bf(hi) << 16);
    }
    ((uint4*)out)[i] = make_uint4(ov[0],ov[1],ov[2],ov[3]);
}

// ---------------- bf16-native MFMA GEMM (m97 structure) ----------------
// EPI: 0 none, 2 gelu, 3 silu, 4 emul*silu, 5 silu on cols>=DI (in_proj z-half)
template<int EPI>
__launch_bounds__(256)
__global__ void bgemm(const ushort_t* __restrict__ A, int lda,
                      const ushort_t* __restrict__ W,
                      const float* __restrict__ bias,
                      const float* __restrict__ emul,
                      float* __restrict__ C,
                      ushort_t* __restrict__ Cb,
                      int ldc, int Ksub, int Nvalid, int accflag, size_t zstride)
{
    __shared__ __align__(16) ushort_t As[128*32];
    __shared__ __align__(16) ushort_t Bs[128*32];
    int t = threadIdx.x;
    int lane = t & 63;
    int w  = t >> 6;
    int wr = w >> 1, wc = w & 1;
    int l15 = lane & 15, quad = lane >> 4;
    const int tileM = blockIdx.y * 128;
    const int tileN = blockIdx.x * 128;
    const int kbeg = blockIdx.z * Ksub;
    const int kend = kbeg + Ksub;

    int srow = w*32 + (lane >> 2);
    int scol = (lane & 3) * 8;
    const ushort_t* gA0 = A + (size_t)(tileM + srow)*lda + scol;
    const ushort_t* gA1 = gA0 + (size_t)16*lda;
    const ushort_t* gW0 = W + (size_t)(tileN + srow)*Ksub*gridDim.z + scol;
    const ushort_t* gW1 = gW0 + (size_t)16*Ksub*gridDim.z;
    ushort_t* ldsA = As + w*1024;
    ushort_t* ldsB = Bs + w*1024;

    f32x4_t acc[4][4];
    #pragma unroll
    for (int i=0;i<4;++i)
        #pragma unroll
        for (int j=0;j<4;++j)
            acc[i][j] = (f32x4_t){0.f,0.f,0.f,0.f};

    for (int kt = kbeg; kt < kend; kt += 32) {
        __syncthreads();
        gload16(gA0 + kt, ldsA);
        gload16(gA1 + kt, ldsA + 512);
        gload16(gW0 + kt, ldsB);
        gload16(gW1 + kt, ldsB + 512);
        __syncthreads();
        short8_t af[4], bfv[4];
        #pragma unroll
        for (int mi=0;mi<4;++mi)
            af[mi] = *(const short8_t*)&As[(wr*64 + mi*16 + l15)*32 + quad*8];
        #pragma unroll
        for (int ni=0;ni<4;++ni)
            bfv[ni] = *(const short8_t*)&Bs[(wc*64 + ni*16 + l15)*32 + quad*8];
        #pragma unroll
        for (int mi=0;mi<4;++mi)
            #pragma unroll
            for (int ni=0;ni<4;++ni)
                acc[mi][ni] = __builtin_amdgcn_mfma_f32_16x16x32_bf16(af[mi], bfv[ni], acc[mi][ni], 0, 0, 0);
    }

    size_t cbase = zstride * blockIdx.z;
    #pragma unroll
    for (int mi=0;mi<4;++mi) {
        #pragma unroll
        for (int ni=0;ni<4;++ni) {
            int gm0 = tileM + wr*64 + mi*16 + quad*4;
            int gn  = tileN + wc*64 + ni*16 + l15;
            if (gn >= Nvalid) continue;
            float bv = bias ? bias[gn] : 0.f;
            #pragma unroll
            for (int r=0;r<4;++r) {
                size_t off = cbase + (size_t)(gm0 + r)*ldc + gn;
                float v = acc[mi][ni][r] + bv;
                if (EPI==2) v = 0.5f*v*(1.f+erff(v*0.70710678118654752440f));
                else if (EPI==3) v = v*sigmoidf_(v);
                else if (EPI==4) v = emul[off] * (v*sigmoidf_(v));
                else if (EPI==5) { if (gn >= DI) v = v*sigmoidf_(v); }
                if (C) { if (accflag) C[off] += v; else C[off] = v; }
                if (Cb) Cb[off] = f2bf(v);
            }
        }
    }
}

// ---------------- batched depthwise causal conv (k=4) + silu, vectorized 8 bf16/thread ----------------
__launch_bounds__(256)
__global__ void conv3_kernel(const ushort_t* __restrict__ xz1,
                             const ushort_t* __restrict__ xz2,
                             const float* __restrict__ cw,
                             const float* __restrict__ cb,
                             ushort_t* __restrict__ xc3)
{
    size_t idx = (size_t)blockIdx.x*256 + threadIdx.x;   // 3*BL*DI/8
    int d8 = (int)(idx & (DI/8 - 1)) * 8;
    size_t rowg = idx >> 7;               // 0..3*BL-1
    int l  = (int)(rowg & (SEQ-1));
    int zb = (int)(rowg >> 11);           // br*4 + b
    int b  = zb & 3, br = zb >> 2;
    int rev = (br == 1);
    const ushort_t* xz = (br < 2) ? xz1 : xz2;
    float acc[8];
    {
        float4 c0 = *(const float4*)(cb + d8);
        float4 c1 = *(const float4*)(cb + d8 + 4);
        acc[0]=c0.x; acc[1]=c0.y; acc[2]=c0.z; acc[3]=c0.w;
        acc[4]=c1.x; acc[5]=c1.y; acc[6]=c1.z; acc[7]=c1.w;
    }
    float wk[8][4];
    #pragma unroll
    for (int j=0;j<8;++j) {
        float4 c = *(const float4*)(cw + (d8+j)*4);
        wk[j][0]=c.x; wk[j][1]=c.y; wk[j][2]=c.z; wk[j][3]=c.w;
    }
    #pragma unroll
    for (int k = 0; k < 4; ++k) {
        int ts = l + k - 3;
        if (ts >= 0) {
            int tin = rev ? (SEQ-1-ts) : ts;
            uint4 v = *(const uint4*)(xz + ((size_t)b*SEQ + tin)*2048 + d8);
            unsigned int uu[4] = {v.x, v.y, v.z, v.w};
            #pragma unroll
            for (int j=0;j<8;++j) {
                ushort_t bb = (ushort_t)((uu[j>>1] >> ((j&1)*16)) & 0xffffu);
                acc[j] = fmaf(wk[j][k], bf2f(bb), acc[j]);
            }
        }
    }
    unsigned int ov[4];
    #pragma unroll
    for (int q=0;q<4;++q) {
        float a0 = acc[2*q],   s0 = a0 * sigmoidf_(a0);
        float a1 = acc[2*q+1], s1 = a1 * sigmoidf_(a1);
        ov[q] = (unsigned int)f2bf(s0) | ((unsigned int)f2bf(s1) << 16);
    }
    *(uint4*)(xc3 + rowg*DI + d8) = make_uint4(ov[0],ov[1],ov[2],ov[3]);
}

// ================= batched chunked selective scan =================
// delta computed per t-group via MFMA (idle matrix pipe) from bf16 dt-input;
// B/C staged compact fp32; z pre-silu'd in in_proj epilogue.
__launch_bounds__(256)
__global__ void scan3_a(const ushort_t* __restrict__ xc3,
                        const float* __restrict__ xdbc,
                        const ushort_t* __restrict__ dti,
                        const ushort_t* __restrict__ dtwb,
                        const float* __restrict__ dtb,
                        const float* __restrict__ A_log,
                        float* __restrict__ hout,
                        float* __restrict__ aprod)
{
    __shared__ __align__(16) float    sbc[CH*32];    // B/C cols, 16 KB
    __shared__ __align__(16) ushort_t sdta[CH*32];   // dt-input bf16, 8 KB
    __shared__ ushort_t sdel[TG*256];                // delta bf16, 16 KB
    int tid = threadIdx.x;
    int lane = tid & 63, w = tid >> 6;
    int l15 = lane & 15, quad = lane >> 4;
    int c = blockIdx.y, zb = blockIdx.z;
    int d0 = blockIdx.x*256;
    int d  = d0 + tid;
    size_t rbase = (size_t)zb*SEQ + (size_t)c*CH;
    {
        const float4* s = (const float4*)(xdbc + rbase*32);
        for (int i = tid; i < CH*8; i += 256) ((float4*)sbc)[i] = s[i];
        const uint4* s2 = (const uint4*)(dti + rbase*32);
        for (int i = tid; i < CH*4; i += 256) ((uint4*)sdta)[i] = s2[i];
    }
    short8_t bfr[4]; float dtbl[4];
    #pragma unroll
    for (int j=0;j<4;++j){
        int dl = w*64 + j*16 + l15;
        bfr[j] = *(const short8_t*)(dtwb + (size_t)(d0+dl)*DR + quad*8);
        dtbl[j] = dtb[d0+dl];
    }
    float An[DS];
    #pragma unroll
    for (int n=0;n<DS;++n) An[n] = -__expf(A_log[(size_t)d*DS+n]);
    float h[DS], P[DS];
    #pragma unroll
    for (int n=0;n<DS;++n) { h[n]=0.f; P[n]=1.f; }
    __syncthreads();
    for (int g=0; g<CH/TG; ++g) {
        if (g) __syncthreads();
        #pragma unroll
        for (int tt=0; tt<2; ++tt) {
            short8_t af = *(const short8_t*)&sdta[(g*TG + tt*16 + l15)*32 + quad*8];
            #pragma unroll
            for (int j=0;j<4;++j) {
                f32x4_t dacc = (f32x4_t){0.f,0.f,0.f,0.f};
                dacc = __builtin_amdgcn_mfma_f32_16x16x32_bf16(af, bfr[j], dacc, 0,0,0);
                int dl = w*64 + j*16 + l15;
                #pragma unroll
                for (int r=0;r<4;++r) {
                    float v = dacc[r] + dtbl[j];
                    v = (v > 20.f) ? v : __logf(1.f + __expf(v));
                    sdel[(tt*16 + quad*4 + r)*256 + dl] = f2bf(v);
                }
            }
        }
        __syncthreads();
        int tb = g*TG;
        for (int t=tb; t<tb+TG; ++t) {
            float dv = bf2f(sdel[(t-tb)*256 + tid]);
            float uv = bf2f(xc3[(rbase+t)*DI + d]);
            float du = dv*uv;
            const float* Bv = &sbc[t*32];
            #pragma unroll
            for (int n=0;n<DS;++n) {
                float dA = __expf(dv*An[n]);
                h[n] = fmaf(dA, h[n], du*Bv[n]);
                P[n] *= dA;
            }
        }
    }
    size_t o = (((size_t)zb*NC + c)*DI + d)*DS;
    #pragma unroll
    for (int q=0;q<4;++q) {
        *(float4*)(hout  + o + 4*q) = make_float4(h[4*q],h[4*q+1],h[4*q+2],h[4*q+3]);
        *(float4*)(aprod + o + 4*q) = make_float4(P[4*q],P[4*q+1],P[4*q+2],P[4*q+3]);
    }
}

__launch_bounds__(256)
__global__ void scan3_b(float* __restrict__ hout,
                        const float* __restrict__ aprod)
{
    int idx = blockIdx.x*256 + threadIdx.x;   // 3*BATCH*DI*DS
    int zb = idx >> 14;
    int dn = idx & (DI*DS - 1);
    float hc = 0.f;
    for (int c=0;c<NC;++c) {
        size_t o = ((size_t)zb*NC + c)*(DI*DS) + dn;
        float a = aprod[o], hh = hout[o];
        hout[o] = hc;                 // hin
        hc = fmaf(a, hc, hh);
    }
}

__launch_bounds__(256)
__global__ void scan3_c(const ushort_t* __restrict__ xc3,
                        const float* __restrict__ xdbc,
                        const ushort_t* __restrict__ dti,
                        const ushort_t* __restrict__ xz1,
                        const ushort_t* __restrict__ xz2,
                        const ushort_t* __restrict__ dtwb,
                        const float* __restrict__ dtb,
                        const float* __restrict__ A_log,
                        const float* __restrict__ Dp,
                        const float* __restrict__ hin,
                        ushort_t* __restrict__ yg3)
{
    __shared__ __align__(16) float    sbc[CH*32];
    __shared__ __align__(16) ushort_t sdta[CH*32];
    __shared__ ushort_t sdel[TG*256];
    int tid = threadIdx.x;
    int lane = tid & 63, w = tid >> 6;
    int l15 = lane & 15, quad = lane >> 4;
    int c = blockIdx.y, zb = blockIdx.z;
    int b  = zb & 3, br = zb >> 2;
    int rev = (br == 1);
    const ushort_t* xz = (br < 2) ? xz1 : xz2;
    int d0 = blockIdx.x*256;
    int d  = d0 + tid;
    size_t rbase = (size_t)zb*SEQ + (size_t)c*CH;
    {
        const float4* s = (const float4*)(xdbc + rbase*32);
        for (int i = tid; i < CH*8; i += 256) ((float4*)sbc)[i] = s[i];
        const uint4* s2 = (const uint4*)(dti + rbase*32);
        for (int i = tid; i < CH*4; i += 256) ((uint4*)sdta)[i] = s2[i];
    }
    short8_t bfr[4]; float dtbl[4];
    #pragma unroll
    for (int j=0;j<4;++j){
        int dl = w*64 + j*16 + l15;
        bfr[j] = *(const short8_t*)(dtwb + (size_t)(d0+dl)*DR + quad*8);
        dtbl[j] = dtb[d0+dl];
    }
    float An[DS];
    #pragma unroll
    for (int n=0;n<DS;++n) An[n] = -__expf(A_log[(size_t)d*DS+n]);
    float h[DS];
    size_t o = (((size_t)zb*NC + c)*DI + d)*DS;
    #pragma unroll
    for (int q=0;q<4;++q) {
        float4 hv = *(const float4*)(hin + o + 4*q);
        h[4*q]=hv.x; h[4*q+1]=hv.y; h[4*q+2]=hv.z; h[4*q+3]=hv.w;
    }
    float Dd = Dp[d];
    __syncthreads();
    for (int g=0; g<CH/TG; ++g) {
        if (g) __syncthreads();
        #pragma unroll
        for (int tt=0; tt<2; ++tt) {
            short8_t af = *(const short8_t*)&sdta[(g*TG + tt*16 + l15)*32 + quad*8];
            #pragma unroll
            for (int j=0;j<4;++j) {
                f32x4_t dacc = (f32x4_t){0.f,0.f,0.f,0.f};
                dacc = __builtin_amdgcn_mfma_f32_16x16x32_bf16(af, bfr[j], dacc, 0,0,0);
                int dl = w*64 + j*16 + l15;
                #pragma unroll
                for (int r=0;r<4;++r) {
                    float v = dacc[r] + dtbl[j];
                    v = (v > 20.f) ? v : __logf(1.f + __expf(v));
                    sdel[(tt*16 + quad*4 + r)*256 + dl] = f2bf(v);
                }
            }
        }
        __syncthreads();
        int tb = g*TG;
        for (int t=tb; t<tb+TG; ++t) {
            float dv = bf2f(sdel[(t-tb)*256 + tid]);
            float uv = bf2f(xc3[(rbase+t)*DI + d]);
            float du = dv*uv;
            const float* Bv = &sbc[t*32];
            const float* Cv = &sbc[t*32 + 16];
            int l = c*CH + t;
            int tz = rev ? (SEQ-1-l) : l;
            float zg = bf2f(xz[((size_t)b*SEQ + tz)*2048 + DI + d]);  // pre-silu'd
            float y = 0.f;
            #pragma unroll
            for (int n=0;n<DS;++n) {
                float dA = __expf(dv*An[n]);
                h[n] = fmaf(dA, h[n], du*Bv[n]);
                y = fmaf(h[n], Cv[n], y);
            }
            yg3[(rbase+t)*DI + d] = f2bf((y + uv*Dd) * zg);
        }
    }
}

// ---------------- layernorm over d=512 ----------------
__launch_bounds__(256)
__global__ void ln_kernel(const float* __restrict__ a, const float* __restrict__ res,
                          const float* __restrict__ g, const float* __restrict__ bta,
                          float* __restrict__ out, ushort_t* __restrict__ outb, float eps)
{
    size_t row = blockIdx.x;
    int t = threadIdx.x;
    const float* ap = a + row*DM;
    float v0 = ap[t], v1 = ap[t+256];
    if (res) { const float* rp = res + row*DM; v0 += rp[t]; v1 += rp[t+256]; }
    float s = v0+v1, q = v0*v0 + v1*v1;
    #pragma unroll
    for (int o=32;o>0;o>>=1){ s += __shfl_xor(s,o); q += __shfl_xor(q,o); }
    __shared__ float ss[4], sq[4];
    int w = t>>6;
    if ((t&63)==0){ ss[w]=s; sq[w]=q; }
    __syncthreads();
    s = ss[0]+ss[1]+ss[2]+ss[3];
    q = sq[0]+sq[1]+sq[2]+sq[3];
    float mean = s * (1.f/DM);
    float var  = q * (1.f/DM) - mean*mean;
    var = var < 0.f ? 0.f : var;
    float rstd = rsqrtf(var + eps);
    float o0 = (v0-mean)*rstd*g[t]     + bta[t];
    float o1 = (v1-mean)*rstd*g[t+256] + bta[t+256];
    if (out) { out[row*DM+t] = o0; out[row*DM+t+256] = o1; }
    if (outb){ outb[row*DM+t] = f2bf(o0); outb[row*DM+t+256] = f2bf(o1); }
}

__launch_bounds__(256)
__global__ void gate_ln_kernel(const float* __restrict__ ha, const float* __restrict__ hb,
                               const float* __restrict__ mo,
                               const float* __restrict__ g, const float* __restrict__ bta,
                               float* __restrict__ out, ushort_t* __restrict__ outb, float eps)
{
    size_t row = blockIdx.x;
    int t = threadIdx.x;
    size_t i0 = row*DM + t, i1 = i0 + 256;
    float a0 = ha[i0], a1 = ha[i1];
    float v0 = fmaf(a0, hb[i0], a0) + mo[i0];
    float v1 = fmaf(a1, hb[i1], a1) + mo[i1];
    float s = v0+v1, q = v0*v0 + v1*v1;
    #pragma unroll
    for (int o=32;o>0;o>>=1){ s += __shfl_xor(s,o); q += __shfl_xor(q,o); }
    __shared__ float ss[4], sq[4];
    int w = t>>6;
    if ((t&63)==0){ ss[w]=s; sq[w]=q; }
    __syncthreads();
    s = ss[0]+ss[1]+ss[2]+ss[3];
    q = sq[0]+sq[1]+sq[2]+sq[3];
    float mean = s * (1.f/DM);
    float var  = q * (1.f/DM) - mean*mean;
    var = var < 0.f ? 0.f : var;
    float rstd = rsqrtf(var + eps);
    float o0 = (v0-mean)*rstd*g[t]     + bta[t];
    float o1 = (v1-mean)*rstd*g[t+256] + bta[t+256];
    out[i0] = o0; out[i1] = o1;
    outb[row*DM+t] = f2bf(o0); outb[row*DM+t+256] = f2bf(o1);
}

// ================= host side =================
static void launch_bgemm(int epi, const ushort_t* A, int lda, const ushort_t* W,
                         const float* bias, const float* emul,
                         float* C, ushort_t* Cb, int ldc, int Mrows, int Ngrid, int K,
                         int Nvalid, int accf, hipStream_t s)
{
    dim3 g(Ngrid/128, Mrows/128, 1);
    switch (epi) {
    case 0: bgemm<0><<<g,256,0,s>>>(A,lda,W,bias,emul,C,Cb,ldc,K,Nvalid,accf,0); break;
    case 2: bgemm<2><<<g,256,0,s>>>(A,lda,W,bias,emul,C,Cb,ldc,K,Nvalid,accf,0); break;
    case 3: bgemm<3><<<g,256,0,s>>>(A,lda,W,bias,emul,C,Cb,ldc,K,Nvalid,accf,0); break;
    case 4: bgemm<4><<<g,256,0,s>>>(A,lda,W,bias,emul,C,Cb,ldc,K,Nvalid,accf,0); break;
    case 5: bgemm<5><<<g,256,0,s>>>(A,lda,W,bias,emul,C,Cb,ldc,K,Nvalid,accf,0); break;
    }
}

static void cast4(const float* in, ushort_t* out, int n, hipStream_t s)
{
    cast4_kernel<<<(n/4 + 255)/256, 256, 0, s>>>(in, out, n/4);
}

extern "C" void kernel_launch(void* const* d_in, const int* in_sizes, int n_in,
                              void* d_out, int out_size, void* d_ws, size_t ws_size,
                              hipStream_t stream)
{
    const float* x        = (const float*)d_in[0];
    const float* fre      = (const float*)d_in[1];
    const float* fim      = (const float*)d_in[2];
    const float* cutoff   = (const float*)d_in[3];
    const float* ln0_g    = (const float*)d_in[4];
    const float* ln0_b    = (const float*)d_in[5];
    const float* l1_w     = (const float*)d_in[6];
    const float* l1_b     = (const float*)d_in[7];
    const float* l2_w     = (const float*)d_in[8];
    const float* l2_b     = (const float*)d_in[9];
    const float* in_w     = (const float*)d_in[10];
    const float* conv_w   = (const float*)d_in[11];
    const float* conv_b   = (const float*)d_in[12];
    const float* xproj_w  = (const float*)d_in[13];
    const float* dt_w     = (const float*)d_in[14];
    const float* dt_b     = (const float*)d_in[15];
    const float* A_log    = (const float*)d_in[16];
    const float* Dp       = (const float*)d_in[17];
    const float* out_w    = (const float*)d_in[18];
    const float* ln1_g    = (const float*)d_in[19];
    const float* ln1_b    = (const float*)d_in[20];
    const float* d1_w     = (const float*)d_in[21];
    const float* d1_b     = (const float*)d_in[22];
    const float* d2_w     = (const float*)d_in[23];
    const float* d2_b     = (const float*)d_in[24];
    const float* ln2_g    = (const float*)d_in[25];
    const float* ln2_b    = (const float*)d_in[26];
    const float* ffn_w1   = (const float*)d_in[27];
    const float* ffn_b1   = (const float*)d_in[28];
    const float* ffn_w2   = (const float*)d_in[29];
    const float* ffn_b2   = (const float*)d_in[30];
    const float* ffn_ln_g = (const float*)d_in[31];
    const float* ffn_ln_b = (const float*)d_in[32];

    float* ws = (float*)d_ws;
    float* RK = ws;                                  // 1024
    float* WFf = RK + 1024;                          // bf16 weight pool backing
    ushort_t* MCb  = (ushort_t*)WFf;                 // 512*512
    ushort_t* L1b  = MCb  + 262144;
    ushort_t* L2b  = L1b  + 262144;
    ushort_t* INb  = L2b  + 262144;                  // 2048*512
    ushort_t* OUTb = INb  + 1048576;                 // 512*1024
    ushort_t* D1b  = OUTb + 524288;
    ushort_t* D2b  = D1b  + 262144;
    ushort_t* F1b  = D2b  + 262144;                  // 2048*512
    ushort_t* F2b  = F1b  + 1048576;                 // 512*2048
    ushort_t* XPb  = F2b  + 1048576;                 // 128*1024
    ushort_t* DTWb = XPb  + 131072;                  // 1024*32
    float* P = WFf + 2572288;                        // 20,971,520-float multi-stage pool
    // -- stage 1-2 --
    ushort_t* XNb = (ushort_t*)P;                    // bf16 xn
    ushort_t* XGb = (ushort_t*)(P + 2097152);        // bf16 xg
    float*    T1a = P + 4194304;                     // fp32 l1-out
    ushort_t* XBx = (ushort_t*)(P + 8388608);        // bf16 x
    // -- stage 3 --
    float*    XDbc = P;                              // 3BL*32 fp32 (B/C)     786,432
    ushort_t* DTi  = (ushort_t*)(P + 786432);        // 3BL*32 bf16           393,216 f
    ushort_t* YG3b = (ushort_t*)(P + 1179648);       // 3*BL*DI bf16       12,582,912 f
    float*    XDP  = P + 13762560;                   // 4*3BL*64 transient  6,291,456
    float*    HOUT = P + 13762560;                   // 3,145,728 (after XDP dead)
    float*    APR  = P + 16908288;                   // 3,145,728 -> ends 20,054,016
    // -- stage 4-6 --
    float*    MOf = P;                               // fp32 mo
    ushort_t* MOb = (ushort_t*)(P + 4194304);        // bf16 mo
    float*    T2g = P + 6291456;                     // fp32 hb
    float*    T1g = P + 10485760;                    // fp32 ha, then ffn2-out
    float*    HSf = P + 14680064;                    // fp32 hs
    ushort_t* HSb = (ushort_t*)(P + 18874368);       // bf16 hs
    // -- large bf16 activations --
    float* XZ1f = P + 20971520;
    ushort_t* XZ1b = (ushort_t*)XZ1f;                // BL*2048 bf16; later FFN hidden
    ushort_t* FHb  = XZ1b;
    float* XZ2f = XZ1f + 8388608;
    ushort_t* XZ2b = (ushort_t*)XZ2f;                // BL*2048 bf16
    float* XC3f = XZ2f + 8388608;
    ushort_t* XC3b = (ushort_t*)XC3f;                // 3*BL*DI bf16 conv-out
    float*    XI   = XC3f;                           // fp32 xi (dead before conv)
    ushort_t* YGb  = (ushort_t*)XC3f;                // bf16 summed yg (after XC dead)
    float* MS = XC3f + 12582912;                     // fp32 out_proj result
    float* OUT = (float*)d_out;

    // 0) weight conversions
    cast4(l1_w,  L1b,  512*512,  stream);
    cast4(l2_w,  L2b,  512*512,  stream);
    cast4(in_w,  INb,  2048*512, stream);
    cast4(out_w, OUTb, 512*1024, stream);
    cast4(d1_w,  D1b,  512*512,  stream);
    cast4(d2_w,  D2b,  512*512,  stream);
    cast4(ffn_w1,F1b,  2048*512, stream);
    cast4(ffn_w2,F2b,  512*2048, stream);
    cast4(dt_w,  DTWb, 1024*32,  stream);
    cast_xproj_kernel<<<512,256,0,stream>>>(xproj_w, XPb);
    cast4(x, XBx, BL*DM, stream);

    // 1) circulant bf16 GEMM, then LN(xi + x) -> bf16 xn
    build_filter_kernel<<<512,256,0,stream>>>(fre, fim, cutoff, RK);
    circ_expand_kernel<<<512,512,0,stream>>>(RK, MCb);
    launch_bgemm(0, XBx,DM, MCb, nullptr, nullptr, XI,nullptr, DM, BL, DM, DM, DM, 0, stream);
    ln_kernel<<<BL,256,0,stream>>>(XI, x, ln0_g, ln0_b, nullptr, XNb, 1e-5f);

    // 2) xg = (xn@l1^T+b1) * silu(xn@l2^T+b2) -> bf16 XGb
    launch_bgemm(0, XNb,DM, L1b, l1_b, nullptr, T1a,nullptr, DM, BL, DM, DM, DM, 0, stream);
    launch_bgemm(4, XNb,DM, L2b, l2_b, T1a, nullptr,XGb, DM, BL, DM, DM, DM, 0, stream);

    // 3) mamba: two in_proj (z-half pre-silu'd), batched conv/xproj/scan
    launch_bgemm(5, XGb,DM, INb, nullptr, nullptr, nullptr,XZ1b, 2048, BL, 2048, DM, 2048, 0, stream);
    launch_bgemm(5, XBx,DM, INb, nullptr, nullptr, nullptr,XZ2b, 2048, BL, 2048, DM, 2048, 0, stream);
    conv3_kernel<<<(3*BL*DI/8)/256,256,0,stream>>>(XZ1b, XZ2b, conv_w, conv_b, XC3b);
    bgemm<0><<<dim3(1, (3*BL)/128, 4),256,0,stream>>>(XC3b,DI, XPb, nullptr, nullptr,
                                                      XDP,nullptr, 64, DI/4, 64, 0, (size_t)3*BL*64);
    reduce_xd_kernel<<<(3*BL*64)/256,256,0,stream>>>(XDP, XDbc, DTi);
    {
        dim3 ga(DI/256, NC, 12);
        scan3_a<<<ga,256,0,stream>>>(XC3b, XDbc, DTi, DTWb, dt_b, A_log, HOUT, APR);
        scan3_b<<<(3*BATCH*DI*DS)/256,256,0,stream>>>(HOUT, APR);
        scan3_c<<<ga,256,0,stream>>>(XC3b, XDbc, DTi, XZ1b, XZ2b, DTWb, dt_b, A_log, Dp, HOUT, YG3b);
    }
    sum3_kernel<<<(BL*DI/8)/256,256,0,stream>>>(YG3b, YGb);
    launch_bgemm(0, YGb,DI, OUTb, nullptr, nullptr, MS,nullptr, DM, BL, DM, DI, DM, 0, stream);

    // 4) mo = LN(m1+m2+m3)
    ln_kernel<<<BL,256,0,stream>>>(MS, nullptr, ln1_g, ln1_b, MOf, MOb, 1e-12f);

    // 5) ha/hb gate + LN -> hs
    launch_bgemm(3, MOb,DM, D1b, d1_b, nullptr, T2g,nullptr, DM, BL, DM, DM, DM, 0, stream);  // hb
    launch_bgemm(0, MOb,DM, D2b, d2_b, nullptr, T1g,nullptr, DM, BL, DM, DM, DM, 0, stream);  // ha
    gate_ln_kernel<<<BL,256,0,stream>>>(T1g, T2g, MOf, ln2_g, ln2_b, HSf, HSb, 1e-12f);

    // 6) FFN
    launch_bgemm(2, HSb,DM, F1b, ffn_b1, nullptr, nullptr,FHb, 2048, BL, 2048, DM, 2048, 0, stream);
    launch_bgemm(0, FHb,2048, F2b, ffn_b2, nullptr, T1g,nullptr, DM, BL, DM, 2048, DM, 0, stream);
    ln_kernel<<<BL,256,0,stream>>>(T1g, HSf, ffn_ln_g, ffn_ln_b, OUT, nullptr, 1e-12f);
}